// Round 2
// baseline (3209.736 us; speedup 1.0000x reference)
//
#include <hip/hip_runtime.h>
#include <math.h>

#define BB 32
#define NN 1024
#define KK 20
typedef unsigned long long u64;
typedef unsigned int u32;
static constexpr float EPSF = 1e-5f;

// ---------------- transpose (B,N,3) -> (B,3,N) ----------------
__global__ void transpose3_kernel(const float* __restrict__ x, float* __restrict__ xT) {
  int t = blockIdx.x * blockDim.x + threadIdx.x;
  if (t >= BB * NN) return;
  int b = t >> 10, i = t & (NN - 1);
  #pragma unroll
  for (int c = 0; c < 3; ++c)
    xT[((size_t)b * 3 + c) * NN + i] = x[(size_t)t * 3 + c];
}

// ---------------- xx = sum(x*x) per point (sequential-c fma chain) ----------------
template<int C>
__global__ void xx_kernel(const float* __restrict__ x, float* __restrict__ xx) {
  int t = blockIdx.x * blockDim.x + threadIdx.x;
  if (t >= BB * NN) return;
  const float* p = x + (size_t)t * C;
  float s = 0.f;
  #pragma unroll
  for (int c = 0; c < C; ++c) s += p[c] * p[c];
  xx[t] = s;
}

// ---------------- sorted top-20 insert on packed u64 keys ----------------
__device__ __forceinline__ void ins20(u64 (&key)[KK], u64 k) {
  if (k > key[KK - 1]) {
    #pragma unroll
    for (int s = KK - 1; s >= 1; --s)
      key[s] = (k > key[s - 1]) ? key[s - 1] : ((k > key[s]) ? k : key[s]);
    key[0] = (k > key[0]) ? k : key[0];
  }
}

__device__ __forceinline__ u64 mkkey(float d, int j) {
  u32 bits = __float_as_uint(d);
  u32 m = (bits & 0x80000000u) ? ~bits : (bits | 0x80000000u);
  return ((u64)m << 32) | (u32)(~(u32)j);
}

// ---------------- dist GEMM: D[bg][i][j] = 2*dot(x_i,x_j) - xx_i - xx_j ----------------
// tile 128x128, K=64, thread computes 8x8. LDS xor-swizzled at float4 granularity.
#define TI 128
#define CC 64
__global__ __launch_bounds__(256) void dist_kernel(
    const float* __restrict__ x,   // (B,N,64)
    const float* __restrict__ xx,  // (B,N)
    float* __restrict__ D,         // (g,N,N)
    int b0) {
  int b = b0 + blockIdx.z;
  int i0 = blockIdx.y * TI;
  int j0 = blockIdx.x * TI;

  __shared__ float4 At[TI * (CC / 4)];
  __shared__ float4 Bt[TI * (CC / 4)];

  const float4* xa = (const float4*)(x + ((size_t)b * NN + i0) * CC);
  const float4* xb = (const float4*)(x + ((size_t)b * NN + j0) * CC);
  #pragma unroll
  for (int t = threadIdx.x; t < TI * (CC / 4); t += 256) {
    int row = t >> 4, c4 = t & 15;
    int c4s = c4 ^ ((row >> 3) & 7);
    At[row * 16 + c4s] = xa[t];
    Bt[row * 16 + c4s] = xb[t];
  }
  __syncthreads();

  int tx = threadIdx.x & 15, ty = threadIdx.x >> 4;
  int ar[8], br[8], asw[8], bsw[8];
  #pragma unroll
  for (int r = 0; r < 8; ++r) {
    int row = ty * 8 + r, col = tx * 8 + r;
    ar[r] = row * 16; asw[r] = (row >> 3) & 7;
    br[r] = col * 16; bsw[r] = (col >> 3) & 7;
  }

  float acc[8][8];
  #pragma unroll
  for (int r = 0; r < 8; ++r)
    #pragma unroll
    for (int s = 0; s < 8; ++s) acc[r][s] = 0.f;

  #pragma unroll
  for (int c4 = 0; c4 < 16; ++c4) {
    float4 av[8], bv[8];
    #pragma unroll
    for (int r = 0; r < 8; ++r) av[r] = At[ar[r] + (c4 ^ asw[r])];
    #pragma unroll
    for (int s = 0; s < 8; ++s) bv[s] = Bt[br[s] + (c4 ^ bsw[s])];
    #pragma unroll
    for (int r = 0; r < 8; ++r)
      #pragma unroll
      for (int s = 0; s < 8; ++s) {
        acc[r][s] += av[r].x * bv[s].x;
        acc[r][s] += av[r].y * bv[s].y;
        acc[r][s] += av[r].z * bv[s].z;
        acc[r][s] += av[r].w * bv[s].w;
      }
  }

  const float* xxb = xx + (size_t)b * NN;
  float xxi[8], xxj[8];
  #pragma unroll
  for (int r = 0; r < 8; ++r) { xxi[r] = xxb[i0 + ty * 8 + r]; xxj[r] = xxb[j0 + tx * 8 + r]; }

  float* Dg = D + (size_t)blockIdx.z * NN * NN;
  #pragma unroll
  for (int r = 0; r < 8; ++r) {
    float4 o0, o1;
    o0.x = 2.f * acc[r][0] - xxi[r] - xxj[0];
    o0.y = 2.f * acc[r][1] - xxi[r] - xxj[1];
    o0.z = 2.f * acc[r][2] - xxi[r] - xxj[2];
    o0.w = 2.f * acc[r][3] - xxi[r] - xxj[3];
    o1.x = 2.f * acc[r][4] - xxi[r] - xxj[4];
    o1.y = 2.f * acc[r][5] - xxi[r] - xxj[5];
    o1.z = 2.f * acc[r][6] - xxi[r] - xxj[6];
    o1.w = 2.f * acc[r][7] - xxi[r] - xxj[7];
    float4* dst = (float4*)(Dg + (size_t)(i0 + ty * 8 + r) * NN + j0 + tx * 8);
    dst[0] = o0; dst[1] = o1;
  }
}

// ---------------- select: per (bg,row,chunk) thread -> sorted top-20 of 128 cands ----------------
#define NCH 8
__global__ __launch_bounds__(256) void select_kernel(
    const float* __restrict__ D,  // (g,N,N)
    u64* __restrict__ P,          // (B,N,NCH,KK)
    int b0) {
  int t = blockIdx.x * 256 + threadIdx.x;   // g*NCH*N threads, row fastest
  int row = t & (NN - 1);
  int ch  = (t >> 10) & (NCH - 1);
  int bg  = t >> 13;

  const float4* dp = (const float4*)(D + ((size_t)bg * NN + row) * NN + ch * (NN / NCH));
  int jbase = ch * (NN / NCH);

  u64 key[KK];
  #pragma unroll
  for (int e = 0; e < KK; ++e) key[e] = 0ull;

  #pragma unroll 4
  for (int q = 0; q < NN / NCH / 4; ++q) {
    float4 v = dp[q];
    int j = jbase + q * 4;
    ins20(key, mkkey(v.x, j + 0));
    ins20(key, mkkey(v.y, j + 1));
    ins20(key, mkkey(v.z, j + 2));
    ins20(key, mkkey(v.w, j + 3));
  }

  u64* out = P + (((size_t)(b0 + bg) * NN + row) * NCH + ch) * KK;
  #pragma unroll
  for (int e = 0; e < KK; ++e) out[e] = key[e];
}

// ---------------- select3: layer-1 fused distance (C=3) ----------------
__global__ __launch_bounds__(256) void select3_kernel(
    const float* __restrict__ x,   // (B,N,3)
    const float* __restrict__ xT,  // (B,3,N)
    const float* __restrict__ xx,  // (B,N)
    u64* __restrict__ P) {         // (B,N,NCH,KK)
  int t = blockIdx.x * 256 + threadIdx.x;   // B*NCH*N threads
  int row = t & (NN - 1);
  int ch  = (t >> 10) & (NCH - 1);
  int b   = t >> 13;

  const float* xr = x + ((size_t)b * NN + row) * 3;
  float x0 = xr[0], x1 = xr[1], x2 = xr[2];
  const float* xxb = xx + (size_t)b * NN;
  float xxi = xxb[row];
  const float* xTb = xT + (size_t)b * 3 * NN;
  int jbase = ch * (NN / NCH);

  u64 key[KK];
  #pragma unroll
  for (int e = 0; e < KK; ++e) key[e] = 0ull;

  for (int q = 0; q < NN / NCH / 4; ++q) {
    int j = jbase + q * 4;
    float4 a = *(const float4*)(xTb + 0 * NN + j);
    float4 bv = *(const float4*)(xTb + 1 * NN + j);
    float4 c = *(const float4*)(xTb + 2 * NN + j);
    float4 xj = *(const float4*)(xxb + j);
    float d0 = 0.f, d1 = 0.f, d2 = 0.f, d3 = 0.f;
    d0 += x0 * a.x; d0 += x1 * bv.x; d0 += x2 * c.x;
    d1 += x0 * a.y; d1 += x1 * bv.y; d1 += x2 * c.y;
    d2 += x0 * a.z; d2 += x1 * bv.z; d2 += x2 * c.z;
    d3 += x0 * a.w; d3 += x1 * bv.w; d3 += x2 * c.w;
    ins20(key, mkkey(2.f * d0 - xxi - xj.x, j + 0));
    ins20(key, mkkey(2.f * d1 - xxi - xj.y, j + 1));
    ins20(key, mkkey(2.f * d2 - xxi - xj.z, j + 2));
    ins20(key, mkkey(2.f * d3 - xxi - xj.w, j + 3));
  }

  u64* out = P + (((size_t)b * NN + row) * NCH + ch) * KK;
  #pragma unroll
  for (int e = 0; e < KK; ++e) out[e] = key[e];
}

// ---------------- merge NCH sorted lists -> final idx ----------------
__global__ __launch_bounds__(256) void merge_kernel(
    const u64* __restrict__ P, int* __restrict__ oidx) {
  int t = blockIdx.x * 256 + threadIdx.x;   // B*N threads
  if (t >= BB * NN) return;
  const u64* p = P + (size_t)t * NCH * KK;

  u64 best[KK];
  #pragma unroll
  for (int e = 0; e < KK; ++e) best[e] = 0ull;

  for (int l = 0; l < NCH; ++l) {
    const u64* pl = p + l * KK;
    for (int e = 0; e < KK; ++e) {
      u64 k = pl[e];
      if (k <= best[KK - 1]) break;   // list sorted desc -> rest smaller
      #pragma unroll
      for (int s = KK - 1; s >= 1; --s)
        best[s] = (k > best[s - 1]) ? best[s - 1] : ((k > best[s]) ? k : best[s]);
      best[0] = (k > best[0]) ? k : best[0];
    }
  }
  int* orow = oidx + (size_t)t * KK;
  #pragma unroll
  for (int e = 0; e < KK; ++e) orow[e] = (int)(~(u32)best[e]);
}

// ---------------- fused gather + edgeconv + BN/ReLU + max over k ----------------
template<int C, int O>
__global__ __launch_bounds__(256) void edge_kernel(
    const float* __restrict__ x,     // (B,N,C)
    const int*   __restrict__ idx,   // (B,N,K)
    const float* __restrict__ w,     // (O,2C)
    const float* __restrict__ g,
    const float* __restrict__ bb,
    float* __restrict__ y) {         // (B,N,O)
  constexpr int NPB = 256 / O;
  int b = blockIdx.y;
  int i0 = blockIdx.x * NPB;
  int o = threadIdx.x % O;
  int p = threadIdx.x / O;
  int i = i0 + p;

  __shared__ float xi[NPB][C];
  __shared__ float nbr[NPB][KK][C];
  __shared__ int   sidx[NPB][KK];

  for (int t = threadIdx.x; t < NPB * KK; t += 256)
    sidx[t / KK][t % KK] = idx[((size_t)b * NN + i0 + t / KK) * KK + (t % KK)];
  for (int t = threadIdx.x; t < NPB * C; t += 256)
    xi[t / C][t % C] = x[((size_t)b * NN + i0 + t / C) * C + (t % C)];
  __syncthreads();

  if constexpr (C % 4 == 0) {
    constexpr int C4 = C / 4;
    const float4* x4 = (const float4*)x;
    float4* n4 = (float4*)&nbr[0][0][0];
    for (int t = threadIdx.x; t < NPB * KK * C4; t += 256) {
      int r = t / C4, c4 = t % C4;
      int pp = r / KK, kk = r % KK;
      int j = sidx[pp][kk];
      n4[t] = x4[((size_t)b * NN + j) * C4 + c4];
    }
  } else {
    for (int t = threadIdx.x; t < NPB * KK * C; t += 256) {
      int r = t / C, cc = t % C;
      int pp = r / KK, kk = r % KK;
      int j = sidx[pp][kk];
      nbr[pp][kk][cc] = x[((size_t)b * NN + j) * C + cc];
    }
  }
  __syncthreads();

  float s = g[o] / sqrtf(1.0f + EPSF);
  float bias = bb[o];
  const float* wrow = w + (size_t)o * 2 * C;
  float m = 0.0f;

  if constexpr (C % 4 == 0) {
    constexpr int C4 = C / 4;
    float4 wa[C4];
    const float4* w4 = (const float4*)wrow;
    #pragma unroll
    for (int c4 = 0; c4 < C4; ++c4) wa[c4] = w4[c4];
    float c0 = 0.f;
    const float4* xi4 = (const float4*)&xi[p][0];
    const float4* wb4 = (const float4*)(wrow + C);
    #pragma unroll
    for (int c4 = 0; c4 < C4; ++c4) {
      float4 wb = wb4[c4], xv = xi4[c4], a = wa[c4];
      c0 += (wb.x - a.x) * xv.x + (wb.y - a.y) * xv.y +
            (wb.z - a.z) * xv.z + (wb.w - a.w) * xv.w;
    }
    for (int k = 0; k < KK; ++k) {
      const float4* nv = (const float4*)&nbr[p][k][0];
      float d = c0;
      #pragma unroll
      for (int c4 = 0; c4 < C4; ++c4) {
        float4 v = nv[c4], a = wa[c4];
        d += a.x * v.x + a.y * v.y + a.z * v.z + a.w * v.w;
      }
      m = fmaxf(m, fmaxf(d * s + bias, 0.0f));
    }
  } else {
    float wa[C];
    float c0 = 0.f;
    #pragma unroll
    for (int c = 0; c < C; ++c) { wa[c] = wrow[c]; c0 += (wrow[C + c] - wa[c]) * xi[p][c]; }
    for (int k = 0; k < KK; ++k) {
      float d = c0;
      #pragma unroll
      for (int c = 0; c < C; ++c) d += wa[c] * nbr[p][k][c];
      m = fmaxf(m, fmaxf(d * s + bias, 0.0f));
    }
  }

  y[((size_t)b * NN + i) * O + o] = m;
}

// ---------------- global max pool over N ----------------
template<int O>
__global__ __launch_bounds__(256) void pool_kernel(
    const float* __restrict__ y, float* __restrict__ pooled, int ooff) {
  int b = blockIdx.x;
  int ob = blockIdx.y * 64;
  int lane = threadIdx.x & 63, wv = threadIdx.x >> 6;
  int o = ob + lane;
  const float* yb = y + (size_t)b * NN * O;
  float m = -INFINITY;
  for (int i = wv; i < NN; i += 4)
    m = fmaxf(m, yb[(size_t)i * O + o]);
  __shared__ float red[4][64];
  red[wv][lane] = m;
  __syncthreads();
  if (wv == 0) {
    m = fmaxf(fmaxf(red[0][lane], red[1][lane]), fmaxf(red[2][lane], red[3][lane]));
    pooled[b * 320 + ooff + o] = m;
  }
}

// ---------------- fc ----------------
template<int IN, int OUT, bool BNRELU>
__global__ void fc_kernel(const float* __restrict__ in, const float* __restrict__ W,
                          const float* __restrict__ lb, const float* __restrict__ g,
                          const float* __restrict__ bbias, float* __restrict__ out) {
  int t = blockIdx.x * blockDim.x + threadIdx.x;
  if (t >= BB * OUT) return;
  int b = t / OUT, o = t % OUT;
  const float4* iv = (const float4*)(in + (size_t)b * IN);
  const float4* wv = (const float4*)(W + (size_t)o * IN);
  float acc = 0.f;
  for (int c4 = 0; c4 < IN / 4; ++c4) {
    float4 a = iv[c4], ww = wv[c4];
    acc += a.x * ww.x + a.y * ww.y + a.z * ww.z + a.w * ww.w;
  }
  acc += lb[o];
  if (BNRELU) {
    float s = g[o] / sqrtf(1.0f + EPSF);
    acc = fmaxf(acc * s + bbias[o], 0.0f);
  }
  out[t] = acc;
}

extern "C" void kernel_launch(void* const* d_in, const int* in_sizes, int n_in,
                              void* d_out, int out_size, void* d_ws, size_t ws_size,
                              hipStream_t stream) {
  const float* x   = (const float*)d_in[0];
  const float* w1  = (const float*)d_in[1];
  const float* g1  = (const float*)d_in[2];
  const float* b1  = (const float*)d_in[3];
  const float* w2  = (const float*)d_in[4];
  const float* g2  = (const float*)d_in[5];
  const float* b2  = (const float*)d_in[6];
  const float* w3  = (const float*)d_in[7];
  const float* g3  = (const float*)d_in[8];
  const float* b3  = (const float*)d_in[9];
  const float* w4  = (const float*)d_in[10];
  const float* g4  = (const float*)d_in[11];
  const float* b4  = (const float*)d_in[12];
  const float* lw1 = (const float*)d_in[13];
  const float* lb1 = (const float*)d_in[14];
  const float* g5  = (const float*)d_in[15];
  const float* b5  = (const float*)d_in[16];
  const float* lw2 = (const float*)d_in[17];
  const float* lb2 = (const float*)d_in[18];
  const float* g6  = (const float*)d_in[19];
  const float* b6  = (const float*)d_in[20];
  const float* lw3 = (const float*)d_in[21];
  const float* lb3 = (const float*)d_in[22];
  float* out = (float*)d_out;

  char* ws = (char*)d_ws;
  size_t off = 0;
  auto alloc = [&](size_t bytes) -> char* {
    char* p = ws + off;
    off += (bytes + 255) & ~255ULL;
    return p;
  };
  int*   idx    = (int*)  alloc((size_t)BB * NN * KK * 4);
  float* xx     = (float*)alloc((size_t)BB * NN * 4);
  float* xT0    = (float*)alloc((size_t)BB * 3 * NN * 4);
  float* bufA   = (float*)alloc((size_t)BB * NN * 64 * 4);
  float* bufB   = (float*)alloc((size_t)BB * NN * 64 * 4);
  float* bufC   = (float*)alloc((size_t)BB * NN * 128 * 4);
  float* pooled = (float*)alloc((size_t)BB * 320 * 4);
  float* h1     = (float*)alloc((size_t)BB * 1024 * 4);
  float* h2     = (float*)alloc((size_t)BB * 512 * 4);
  u64*   P      = (u64*)  alloc((size_t)BB * NN * NCH * KK * 8);

  // D gets the remainder: groups of up to 8 batches (keeps D L3-resident)
  size_t dbytes_per_b = (size_t)NN * NN * 4;
  size_t rem = (ws_size > off) ? (ws_size - off) : 0;
  int gmax = (int)(rem / dbytes_per_b);
  if (gmax > 8) gmax = 8;
  if (gmax < 1) gmax = 1;  // trust ws_size >= ~83MB
  float* D = (float*)alloc((size_t)gmax * dbytes_per_b);

  dim3 blk(256);
  int bn_blocks = (BB * NN + 255) / 256;

  auto knn64 = [&](const float* feat) {
    xx_kernel<64><<<bn_blocks, blk, 0, stream>>>(feat, xx);
    for (int b0 = 0; b0 < BB; b0 += gmax) {
      int gg = (BB - b0 < gmax) ? (BB - b0) : gmax;
      dist_kernel<<<dim3(NN / TI, NN / TI, gg), blk, 0, stream>>>(feat, xx, D, b0);
      select_kernel<<<(gg * NCH * NN) / 256, blk, 0, stream>>>(D, P, b0);
    }
    merge_kernel<<<(BB * NN) / 256, blk, 0, stream>>>(P, idx);
  };

  // ---- layer 1 (C=3 -> 64) ----
  transpose3_kernel<<<bn_blocks, blk, 0, stream>>>(x, xT0);
  xx_kernel<3><<<bn_blocks, blk, 0, stream>>>(x, xx);
  select3_kernel<<<(BB * NCH * NN) / 256, blk, 0, stream>>>(x, xT0, xx, P);
  merge_kernel<<<(BB * NN) / 256, blk, 0, stream>>>(P, idx);
  edge_kernel<3, 64><<<dim3(NN / 4, BB), blk, 0, stream>>>(x, idx, w1, g1, b1, bufA);
  pool_kernel<64><<<dim3(BB, 1), blk, 0, stream>>>(bufA, pooled, 0);

  // ---- layer 2 (64 -> 64) ----
  knn64(bufA);
  edge_kernel<64, 64><<<dim3(NN / 4, BB), blk, 0, stream>>>(bufA, idx, w2, g2, b2, bufB);
  pool_kernel<64><<<dim3(BB, 1), blk, 0, stream>>>(bufB, pooled, 64);

  // ---- layer 3 (64 -> 64) ----
  knn64(bufB);
  edge_kernel<64, 64><<<dim3(NN / 4, BB), blk, 0, stream>>>(bufB, idx, w3, g3, b3, bufA);
  pool_kernel<64><<<dim3(BB, 1), blk, 0, stream>>>(bufA, pooled, 128);

  // ---- layer 4 (64 -> 128) ----
  knn64(bufA);
  edge_kernel<64, 128><<<dim3(NN / 2, BB), blk, 0, stream>>>(bufA, idx, w4, g4, b4, bufC);
  pool_kernel<128><<<dim3(BB, 2), blk, 0, stream>>>(bufC, pooled, 192);

  // ---- classifier ----
  fc_kernel<320, 1024, true><<<(BB * 1024 + 255) / 256, blk, 0, stream>>>(pooled, lw1, lb1, g5, b5, h1);
  fc_kernel<1024, 512, true><<<(BB * 512 + 255) / 256, blk, 0, stream>>>(h1, lw2, lb2, g6, b6, h2);
  fc_kernel<512, 40, false><<<(BB * 40 + 255) / 256, blk, 0, stream>>>(h2, lw3, lb3, nullptr, nullptr, out);
}